// Round 8
// baseline (208.454 us; speedup 1.0000x reference)
//
#include <hip/hip_runtime.h>
#include <cstdint>
#include <cstddef>

#define N_ANCH   120000
#define K_PRE    2000
#define K_POST   512
#define CAP      4096
#define NWORD    32          // ceil(K_PRE/64)
#define HBINS    4096        // top-12-bit histogram
#define IOU_THR  0.7f
#define IMGF     800.0f
#define CLIPV    4.135166556742356f
#define FH       200
#define FW       200
#define FC       256
#define SCALE    0.25f

#define TROWS    96          // scan tile rows (96*256B = 24KB; x2 buffers = 48KB LDS)
#define NTILE    21          // ceil(2000/96); last tile = 80 rows
#define CH       8           // scan chunk rows (register prefetch depth)

#define CG       16          // roi: channels per group
#define TPE      4           // rank: threads per element

typedef unsigned long long u64;
typedef float f2u __attribute__((ext_vector_type(2), aligned(4)));

struct Ws {
    uint32_t T;          // PROGRESS counter: #rows published (scan -> roi handoff)
    uint32_t cnt;        // gather counter
    int32_t  nk;         // number kept after NMS
    uint32_t pad;
    u64      combo[CAP];             // (~key)<<32 | index (unsorted)
    float4   cand[K_PRE];            // decoded candidate boxes, score-desc order
    int      rows[K_POST];           // candidate rank per output row, -1 = invalid
    u64      mask[(size_t)K_PRE * NWORD];  // IoU bitmask
    // NOTE: first 16KB of mask doubles as the uint32 hist[4096] (used before mask)
};

// Monotonic float -> uint key (larger float => larger uint). No NaNs expected.
__device__ inline uint32_t fkey(float f) {
    uint32_t u = __float_as_uint(f);
    return (u & 0x80000000u) ? ~u : (u | 0x80000000u);
}

// ---------------------------------------------------------------------------
// Kernel 0: zero the histogram (aliased onto mask region) + counters.
// T=0 is REQUIRED before scan_roi_k's consumers poll it.
// ---------------------------------------------------------------------------
__global__ __launch_bounds__(1024) void zero_k(Ws* __restrict__ ws) {
    uint32_t* h = (uint32_t*)ws->mask;
    for (int i = threadIdx.x; i < HBINS; i += 1024) h[i] = 0u;
    if (threadIdx.x == 0) { ws->cnt = 0u; ws->nk = 0; ws->T = 0u; }
}

// ---------------------------------------------------------------------------
// Kernel 1: grid-wide 4096-bin histogram of top-12 key bits (LDS-privatized).
// ---------------------------------------------------------------------------
__global__ __launch_bounds__(256) void hist_k(const float* __restrict__ obj,
                                              uint32_t* __restrict__ hist) {
    __shared__ uint32_t h[HBINS];
    for (int i = threadIdx.x; i < HBINS; i += 256) h[i] = 0u;
    __syncthreads();
    const float4* o4 = (const float4*)obj;
    for (int i = blockIdx.x * 256 + threadIdx.x; i < N_ANCH / 4; i += gridDim.x * 256) {
        float4 v = o4[i];
        atomicAdd(&h[fkey(v.x) >> 20], 1u);
        atomicAdd(&h[fkey(v.y) >> 20], 1u);
        atomicAdd(&h[fkey(v.z) >> 20], 1u);
        atomicAdd(&h[fkey(v.w) >> 20], 1u);
    }
    __syncthreads();
    for (int i = threadIdx.x; i < HBINS; i += 256)
        if (h[i]) atomicAdd(&hist[i], h[i]);
}

// ---------------------------------------------------------------------------
// Kernel 2 (fused resolve+gather).
// ---------------------------------------------------------------------------
__global__ __launch_bounds__(256) void gather_k(const float* __restrict__ obj,
                                                const uint32_t* __restrict__ hist,
                                                Ws* __restrict__ ws) {
    __shared__ uint32_t wsum[4];
    __shared__ uint32_t sT;
    const int tid = threadIdx.x;
    const int lane = tid & 63, wave = tid >> 6;
    uint32_t c[16]; uint32_t s = 0;
#pragma unroll
    for (int k = 0; k < 16; ++k) { c[k] = hist[HBINS - 1 - (16 * tid + k)]; s += c[k]; }
    uint32_t incl = s;
    for (int off = 1; off < 64; off <<= 1) {
        uint32_t t = __shfl_up(incl, off);
        if (lane >= off) incl += t;
    }
    if (lane == 63) wsum[wave] = incl;
    __syncthreads();
    uint32_t wpre = 0;
    for (int w2 = 0; w2 < wave; ++w2) wpre += wsum[w2];
    uint32_t before = wpre + incl - s;
#pragma unroll
    for (int k = 0; k < 16; ++k) {
        uint32_t after = before + c[k];
        if (before < K_PRE && after >= K_PRE)
            sT = (uint32_t)(HBINS - 1 - (16 * tid + k)) << 20;
        before = after;
    }
    __syncthreads();
    const uint32_t T = sT;
    int i = blockIdx.x * 256 + tid;
    if (i >= N_ANCH / 4) return;
    float4 v = ((const float4*)obj)[i];
    float vals[4] = {v.x, v.y, v.z, v.w};
#pragma unroll
    for (int k = 0; k < 4; ++k) {
        uint32_t u = fkey(vals[k]);
        if (u >= T) {
            uint32_t pos = atomicAdd(&ws->cnt, 1u);
            if (pos < CAP)
                ws->combo[pos] = ((u64)(~u) << 32) | (uint32_t)(4 * i + k);
        }
    }
}

// ---------------------------------------------------------------------------
// Kernel 3: RANK-based ordering + decode.
// ---------------------------------------------------------------------------
__global__ __launch_bounds__(256) void rank_decode_k(const float* __restrict__ deltas,
                                                     const float* __restrict__ anchors,
                                                     Ws* __restrict__ ws) {
    __shared__ u64 sc[CAP];
    const int tid = threadIdx.x;
    int M = (int)ws->cnt;
    if (M > CAP) M = CAP;
    const int ebase = blockIdx.x * (256 / TPE);
    if (ebase >= M) return;
    for (int e = tid; e < M; e += 256) sc[e] = ws->combo[e];
    __syncthreads();
    const int gid = ebase + tid / TPE;
    const int sub = tid & (TPE - 1);
    if (gid >= M) return;
    const u64 mine = sc[gid];
    int cnt = 0;
    int j = sub;
    for (; j + 3 * TPE < M; j += 4 * TPE) {
        u64 a = sc[j], b = sc[j + TPE], c = sc[j + 2 * TPE], d = sc[j + 3 * TPE];
        cnt += (int)(a < mine) + (int)(b < mine) + (int)(c < mine) + (int)(d < mine);
    }
    for (; j < M; j += TPE) cnt += (int)(sc[j] < mine);
    cnt += __shfl_xor(cnt, 1);
    cnt += __shfl_xor(cnt, 2);
    if (sub == 0 && cnt < K_PRE) {
        const uint32_t idx = (uint32_t)(mine & 0xFFFFFFFFull);
        float a0 = anchors[idx * 4 + 0], a1 = anchors[idx * 4 + 1];
        float a2 = anchors[idx * 4 + 2], a3 = anchors[idx * 4 + 3];
        float d0 = deltas[idx * 4 + 0],  d1 = deltas[idx * 4 + 1];
        float d2 = fminf(deltas[idx * 4 + 2], CLIPV);
        float d3 = fminf(deltas[idx * 4 + 3], CLIPV);
        float w = a2 - a0, h = a3 - a1;
        float cx = a0 + 0.5f * w, cy = a1 + 0.5f * h;
        float pcx = d0 * w + cx, pcy = d1 * h + cy;
        float pw = expf(d2) * w, ph = expf(d3) * h;
        float x1 = fminf(fmaxf(pcx - 0.5f * pw, 0.0f), IMGF);
        float y1 = fminf(fmaxf(pcy - 0.5f * ph, 0.0f), IMGF);
        float x2 = fminf(fmaxf(pcx + 0.5f * pw, 0.0f), IMGF);
        float y2 = fminf(fmaxf(pcy + 0.5f * ph, 0.0f), IMGF);
        ws->cand[cnt] = make_float4(x1, y1, x2, y2);
    }
}

// ---------------------------------------------------------------------------
// Kernel 4: build the pairwise suppression bitmask.
// ---------------------------------------------------------------------------
__global__ __launch_bounds__(256) void nms_mask_k(Ws* __restrict__ ws) {
    const int i = blockIdx.x;
    const int lane = threadIdx.x & 63;
    const int wave = threadIdx.x >> 6;
    const float4 bi = ws->cand[i];
    const float ai = (bi.z - bi.x) * (bi.w - bi.y);
    for (int wd = wave; wd < NWORD; wd += 4) {
        int j = wd * 64 + lane;
        bool bit = false;
        if (j < K_PRE && j > i) {
            float4 bj = ws->cand[j];
            float aj = (bj.z - bj.x) * (bj.w - bj.y);
            float xx1 = fmaxf(bi.x, bj.x);
            float yy1 = fmaxf(bi.y, bj.y);
            float xx2 = fminf(bi.z, bj.z);
            float yy2 = fminf(bi.w, bj.w);
            float ww = fmaxf(xx2 - xx1, 0.0f);
            float hh = fmaxf(yy2 - yy1, 0.0f);
            float inter = ww * hh;
            float iou = inter / (ai + aj - inter + 1e-6f);
            bit = iou > IOU_THR;
        }
        u64 bal = __ballot(bit);
        if (lane == 0) ws->mask[(size_t)i * NWORD + wd] = bal;
    }
}

// ---------------------------------------------------------------------------
// Kernel 5 (round-8): fused scan + ROIAlign, RMW-ONLY streaming handoff.
// Round-7 HANG root cause: consumers polled T with RELAXED atomic LOADS,
// which can be served from a stale local cache line on gfx950 (round-6's
// ACQUIRE loads worked because buffer_inv invalidated the line — at the cost
// of 4096 L2 invalidates, FETCH 20->67MB). Fix: ALL handshake traffic uses
// atomic RMW ops, which always execute at the coherence point (LLC):
//  - producer: rows[pos] via atomicExch, s_waitcnt vmcnt(0), T via atomicExch
//    (no buffer_wbl2, unlike round-6's RELEASE which cost ~2us x21 tiles);
//  - consumers: poll atomicAdd(&T,0) (cannot read stale; cannot hang) with
//    s_sleep backoff + 1M-poll safety cap (degrades to absmax-fail, not a
//    container kill), then rows via atomicAdd(ptr,0).
// cand[]/mask[] cross kernel boundaries (implicit flush) — plain loads fine.
// ---------------------------------------------------------------------------
__global__ __launch_bounds__(512) void scan_roi_k(const float* __restrict__ feat,
                                                  Ws* __restrict__ ws,
                                                  float* __restrict__ out) {
    __shared__ __align__(16) u64 sbuf[2][TROWS * NWORD];
    __shared__ int s_stop;
    __shared__ int sRow[2];
    const int tid = threadIdx.x;
    const int lane = tid & 63;
    const int wave = tid >> 6;

    if (blockIdx.x == 0) {
        // ===================== SCAN (producer) =====================
        __builtin_amdgcn_s_setprio(3);       // win issue arbitration on this CU
        const int lmod = lane & 31;
        const u64* __restrict__ mask = ws->mask;
        {
            const ulonglong2* src = (const ulonglong2*)mask;
            ulonglong2* dst = (ulonglong2*)sbuf[0];
            for (int e = tid; e < TROWS * NWORD / 2; e += 512) dst[e] = src[e];
        }
        if (tid == 0) s_stop = 0;
        __syncthreads();

        u64 supp = 0ull;
        int pubtot = 0;                      // rows published so far
        const u64 valid = (lane < NWORD - 1) ? ~0ull
                        : (lane == NWORD - 1 ? ((1ull << (K_PRE - (NWORD - 1) * 64)) - 1ull)
                                             : 0ull);
        for (int t = 0; t < NTILE; ++t) {
            const int base = t * TROWS;
            const int nb = min(TROWS, K_PRE - base);
            if (wave == 0) {
                const u64* sm = sbuf[t & 1];
                u64 A[CH], B[CH];
#pragma unroll
                for (int b = 0; b < CH; ++b) A[b] = sm[b * NWORD + lmod];
                for (int s = 0; s < nb; s += 2 * CH) {
                    const bool hasB = (s + CH) < nb;
                    if (hasB) {
#pragma unroll
                        for (int b = 0; b < CH; ++b) B[b] = sm[(s + CH + b) * NWORD + lmod];
                    }
                    {
                        const int w = (base + s) >> 6;
                        const int bofs = (base + s) & 63;
                        u64 keptw = 0ull;
                        if (lane == w) {
                            u64 cur = supp;
#pragma unroll
                            for (int b = 0; b < CH; ++b) {
                                u64 bit = (cur >> (bofs + b)) & 1ull;
                                u64 sel = bit - 1ull;
                                cur |= A[b] & sel;
                                keptw |= sel & (1ull << b);
                            }
                            supp = cur;
                        }
                        u64 kb = __shfl(keptw, w);
#pragma unroll
                        for (int b = 0; b < CH; ++b) {
                            u64 sel = 0ull - ((kb >> b) & 1ull);
                            supp |= A[b] & sel;
                        }
                    }
                    if (hasB) {
                        if (s + 2 * CH < nb) {
#pragma unroll
                            for (int b = 0; b < CH; ++b)
                                A[b] = sm[(s + 2 * CH + b) * NWORD + lmod];
                        }
                        const int w = (base + s + CH) >> 6;
                        const int bofs = (base + s + CH) & 63;
                        u64 keptw = 0ull;
                        if (lane == w) {
                            u64 cur = supp;
#pragma unroll
                            for (int b = 0; b < CH; ++b) {
                                u64 bit = (cur >> (bofs + b)) & 1ull;
                                u64 sel = bit - 1ull;
                                cur |= B[b] & sel;
                                keptw |= sel & (1ull << b);
                            }
                            supp = cur;
                        }
                        u64 kb = __shfl(keptw, w);
#pragma unroll
                        for (int b = 0; b < CH; ++b) {
                            u64 sel = 0ull - ((kb >> b) & 1ull);
                            supp |= B[b] & sel;
                        }
                    }
                }
                // ---- incremental publish of rows decided in [base, base+nb) ----
                {
                    const int w0 = lane << 6;
                    int lo = base - w0;      if (lo < 0)  lo = 0;
                    int hi = base + nb - w0; if (hi > 64) hi = 64;
                    u64 rmask = 0ull;
                    if (hi > lo) {
                        u64 mh = (hi >= 64) ? ~0ull : ((1ull << hi) - 1ull);
                        u64 ml = (lo <= 0) ? 0ull : ((1ull << lo) - 1ull);
                        rmask = mh & ~ml;
                    }
                    u64 keepn = (~supp) & valid & rmask;
                    int c = __popcll(keepn);
                    int incl = c;
                    for (int off = 1; off < 64; off <<= 1) {
                        int tt = __shfl_up(incl, off);
                        if (lane >= off) incl += tt;
                    }
                    int pos = pubtot + incl - c;
                    u64 kw = keepn;
                    while (kw) {
                        int b = __ffsll((unsigned long long)kw) - 1;
                        kw &= kw - 1ull;
                        if (pos < K_POST)
                            atomicExch((int*)&ws->rows[pos], w0 + b);   // RMW -> LLC
                        ++pos;
                    }
                    pubtot += __shfl(incl, 63);
                    int pr = pubtot < K_POST ? pubtot : K_POST;
                    // Drain rows-atomics (vmcnt covers atomics) BEFORE T bump.
                    asm volatile("s_waitcnt vmcnt(0)" ::: "memory");
                    if (lane == 0) {
                        atomicExch(&ws->T, (uint32_t)pr);               // RMW -> LLC
                        if (pubtot >= K_POST) s_stop = 1;
                    }
                }
            } else if (t + 1 < NTILE) {
                const int nbase = (t + 1) * TROWS;
                const int npairs = (min(TROWS, K_PRE - nbase) * NWORD) / 2;
                const ulonglong2* src = (const ulonglong2*)(mask + (size_t)nbase * NWORD);
                ulonglong2* dst = (ulonglong2*)sbuf[(t + 1) & 1];
                for (int e = tid - 64; e < npairs; e += 448) dst[e] = src[e];
            }
            __syncthreads();
            if (s_stop) break;
        }

        if (wave == 0) {
            for (int rr = pubtot + lane; rr < K_POST; rr += 64)
                atomicExch((int*)&ws->rows[rr], -1);
            asm volatile("s_waitcnt vmcnt(0)" ::: "memory");
            if (lane == 0) {
                ws->nk = pubtot;
                atomicExch(&ws->T, (uint32_t)K_POST);
            }
        }
        return;
    }

    // ===================== ROI (consumers) =====================
    const int u = (int)blockIdx.x - 1;       // 0..4095
    const int q = (u >> 3) & 255;            // roi-pair index, increases with bid
    const int cg = (u & 7) + 8 * (u >> 11);  // phase 0: cg 0..7, phase 1: cg 8..15
    const int h = tid >> 8;                  // half: 0 or 1 -> roi r = 2q+h
    const int tid2 = tid & 255;
    const int r = 2 * q + h;
    const int cbase = cg * CG;

    if (tid == 0) {
        // RMW-poll: always reads the coherence point — cannot see stale data.
        // Safety cap: if the handshake is ever broken, produce wrong-but-
        // finite output instead of a watchdog kill.
        int polls = 0;
        while (atomicAdd(&ws->T, 0u) <= (uint32_t)(2 * q + 1) && polls < (1 << 20)) {
            __builtin_amdgcn_s_sleep(32);
            ++polls;
        }
        sRow[0] = atomicAdd((int*)&ws->rows[2 * q], 0);
        sRow[1] = atomicAdd((int*)&ws->rows[2 * q + 1], 0);
    }
    __syncthreads();
    const int row = sRow[h];
    float* oblk = out + (size_t)r * (FC * 49) + (size_t)cbase * 49;

    if (row < 0) {
        for (int e = tid2; e < CG * 49; e += 256) oblk[e] = 0.0f;
        return;
    }
    if (tid2 >= 245) return;                 // 5 channel slots x 49 bins per half

    const int p = tid2 % 49;
    const int cslot = tid2 / 49;             // 0..4
    const int oy = p / 7, ox = p % 7;

    const float4 bx = ws->cand[row];
    const float x1 = bx.x * SCALE, y1 = bx.y * SCALE;
    const float x2 = bx.z * SCALE, y2 = bx.w * SCALE;
    const float rw = fmaxf(x2 - x1, 1.0f);
    const float rh = fmaxf(y2 - y1, 1.0f);
    const float stepx = rw / 14.0f;
    const float stepy = rh / 14.0f;

    int    off0[4], off1[4];
    float4 w4[4];
#pragma unroll
    for (int sub = 0; sub < 4; ++sub) {
        const int sy = sub >> 1, sx = sub & 1;
        float yy = y1 + ((float)(2 * oy + sy) + 0.5f) * stepy;
        float y = fminf(fmaxf(yy, 0.0f), (float)(FH - 1));
        float fy0 = floorf(y);
        int iy0 = (int)fy0;
        int iy1 = min(iy0 + 1, FH - 1);
        float ly = y - fy0;
        float xx = x1 + ((float)(2 * ox + sx) + 0.5f) * stepx;
        float x = fminf(fmaxf(xx, 0.0f), (float)(FW - 1));
        float fx0 = floorf(x);
        int ix0 = (int)fx0;
        float lx = x - fx0;
        float wxl, wxr; int base;
        if (ix0 >= FW - 1) { base = FW - 2; wxl = 0.0f; wxr = 1.0f; }
        else               { base = ix0;    wxl = 1.0f - lx; wxr = lx; }
        float wy0 = 1.0f - ly, wy1 = ly;
        off0[sub] = iy0 * FW + base;
        off1[sub] = iy1 * FW + base;
        w4[sub] = make_float4(wy0 * wxl * 0.25f, wy0 * wxr * 0.25f,
                              wy1 * wxl * 0.25f, wy1 * wxr * 0.25f);
    }

    // ---- ISSUE PHASE: all scattered loads back-to-back.
    const float* fb = feat + (size_t)cbase * (FH * FW);
    const float* f0 = fb + (size_t)cslot * (FH * FW);
    const float* f1 = fb + (size_t)(cslot + 5) * (FH * FW);
    const float* f2 = fb + (size_t)(cslot + 10) * (FH * FW);
    f2u r0[8], r1[8], r2[8], r3[8];
#pragma unroll
    for (int sub = 0; sub < 4; ++sub) {
        r0[2 * sub]     = *(const f2u*)(f0 + off0[sub]);
        r0[2 * sub + 1] = *(const f2u*)(f0 + off1[sub]);
    }
#pragma unroll
    for (int sub = 0; sub < 4; ++sub) {
        r1[2 * sub]     = *(const f2u*)(f1 + off0[sub]);
        r1[2 * sub + 1] = *(const f2u*)(f1 + off1[sub]);
    }
#pragma unroll
    for (int sub = 0; sub < 4; ++sub) {
        r2[2 * sub]     = *(const f2u*)(f2 + off0[sub]);
        r2[2 * sub + 1] = *(const f2u*)(f2 + off1[sub]);
    }
    const bool has4 = (cslot == 0);
    if (has4) {
        const float* f3 = fb + (size_t)15 * (FH * FW);
#pragma unroll
        for (int sub = 0; sub < 4; ++sub) {
            r3[2 * sub]     = *(const f2u*)(f3 + off0[sub]);
            r3[2 * sub + 1] = *(const f2u*)(f3 + off1[sub]);
        }
    }

    // ---- COMPUTE PHASE: FMAs in load-issue order.
    float a0 = 0.0f, a1 = 0.0f, a2 = 0.0f;
#pragma unroll
    for (int sub = 0; sub < 4; ++sub) {
        a0 += w4[sub].x * r0[2 * sub].x + w4[sub].y * r0[2 * sub].y
            + w4[sub].z * r0[2 * sub + 1].x + w4[sub].w * r0[2 * sub + 1].y;
    }
#pragma unroll
    for (int sub = 0; sub < 4; ++sub) {
        a1 += w4[sub].x * r1[2 * sub].x + w4[sub].y * r1[2 * sub].y
            + w4[sub].z * r1[2 * sub + 1].x + w4[sub].w * r1[2 * sub + 1].y;
    }
#pragma unroll
    for (int sub = 0; sub < 4; ++sub) {
        a2 += w4[sub].x * r2[2 * sub].x + w4[sub].y * r2[2 * sub].y
            + w4[sub].z * r2[2 * sub + 1].x + w4[sub].w * r2[2 * sub + 1].y;
    }
    oblk[cslot * 49 + p] = a0;
    oblk[(cslot + 5) * 49 + p] = a1;
    oblk[(cslot + 10) * 49 + p] = a2;

    if (has4) {
        float a3 = 0.0f;
#pragma unroll
        for (int sub = 0; sub < 4; ++sub) {
            a3 += w4[sub].x * r3[2 * sub].x + w4[sub].y * r3[2 * sub].y
                + w4[sub].z * r3[2 * sub + 1].x + w4[sub].w * r3[2 * sub + 1].y;
        }
        oblk[15 * 49 + p] = a3;
    }
}

extern "C" void kernel_launch(void* const* d_in, const int* in_sizes, int n_in,
                              void* d_out, int out_size, void* d_ws, size_t ws_size,
                              hipStream_t stream) {
    const float* feature    = (const float*)d_in[0];
    const float* objectness = (const float*)d_in[1];
    const float* deltas     = (const float*)d_in[2];
    const float* anchors    = (const float*)d_in[3];
    Ws* ws = (Ws*)d_ws;
    uint32_t* hist = (uint32_t*)ws->mask;   // alias: hist lives in (pre-)mask space
    float* out = (float*)d_out;

    hipLaunchKernelGGL(zero_k, dim3(1), dim3(1024), 0, stream, ws);
    hipLaunchKernelGGL(hist_k, dim3(256), dim3(256), 0, stream, objectness, hist);
    hipLaunchKernelGGL(gather_k, dim3((N_ANCH / 4 + 255) / 256), dim3(256), 0, stream,
                       objectness, hist, ws);
    hipLaunchKernelGGL(rank_decode_k, dim3(CAP / (256 / TPE)), dim3(256), 0, stream,
                       deltas, anchors, ws);
    hipLaunchKernelGGL(nms_mask_k, dim3(K_PRE), dim3(256), 0, stream, ws);
    hipLaunchKernelGGL(scan_roi_k, dim3(1 + 4096), dim3(512), 0, stream,
                       feature, ws, out);
}

// Round 9
// 207.980 us; speedup vs baseline: 1.0023x; 1.0023x over previous
//
#include <hip/hip_runtime.h>
#include <cstdint>
#include <cstddef>

#define N_ANCH   120000
#define K_PRE    2000
#define K_POST   512
#define CAP      4096
#define NWORD    32          // ceil(K_PRE/64)
#define HBINS    4096        // top-12-bit histogram
#define IOU_THR  0.7f
#define IMGF     800.0f
#define CLIPV    4.135166556742356f
#define FH       200
#define FW       200
#define FC       256
#define SCALE    0.25f

#define TROWS    96          // scan tile rows (96*256B = 24KB; x2 buffers = 48KB LDS)
#define NTILE    21          // ceil(2000/96); last tile = 80 rows
#define CH       8           // scan chunk rows (register prefetch depth)

#define CG       16          // roi: channels per group
#define TPE      4           // rank: threads per element

// SESSION LESSON (rounds 3-8, measured): on gfx950 the KERNEL BOUNDARY
// (~8us) is the cheapest grid barrier. Alternatives all measured worse:
// coop grid.sync ~80us/barrier (L2 writeback+inv storm); threadfence+ticket
// ~80us total (2000 buffer_wbl2); single-line RMW polling +25-40us (LLC
// serialization) and relaxed atomic LOADS can read stale lines (r7 hang).
// Structure below: 7 plain kernels, data handoff only at node boundaries.

typedef unsigned long long u64;
typedef float f2u __attribute__((ext_vector_type(2), aligned(4)));

struct Ws {
    uint32_t T;          // (unused)
    uint32_t cnt;        // gather counter
    int32_t  nk;         // number kept after NMS
    uint32_t pad;
    u64      combo[CAP];             // (~key)<<32 | index (unsorted)
    float4   cand[K_PRE];            // decoded candidate boxes, score-desc order
    int      rows[K_POST];           // candidate rank per output row, -1 = invalid
    u64      mask[(size_t)K_PRE * NWORD];  // IoU bitmask
    // NOTE: first 16KB of mask doubles as the uint32 hist[4096] (used before mask)
};
// featT (HWC transpose, 40000*256 f32 = 41MB) lives AFTER Ws in workspace,
// 256B-aligned — host guards on ws_size and falls back to the CHW path.

// Monotonic float -> uint key (larger float => larger uint). No NaNs expected.
__device__ inline uint32_t fkey(float f) {
    uint32_t u = __float_as_uint(f);
    return (u & 0x80000000u) ? ~u : (u | 0x80000000u);
}

// ---------------------------------------------------------------------------
// Kernel 0: zero the histogram (aliased onto mask region) + counters.
// ---------------------------------------------------------------------------
__global__ __launch_bounds__(1024) void zero_k(Ws* __restrict__ ws) {
    uint32_t* h = (uint32_t*)ws->mask;
    for (int i = threadIdx.x; i < HBINS; i += 1024) h[i] = 0u;
    if (threadIdx.x == 0) { ws->cnt = 0u; ws->nk = 0; ws->T = 0u; }
}

// ---------------------------------------------------------------------------
// Kernel 1a (HWC path): fused TRANSPOSE (CHW->HWC) + histogram.
// 1250 blocks: each transposes a 32-pixel x 256-ch tile via LDS (both sides
// coalesced: loads 2x128B segments/wave, stores 1KB rows); blocks 0..117
// additionally run the round-2 histogram slice (same semantics as hist_k).
// Absorbing hist keeps node count at 7.
// ---------------------------------------------------------------------------
__global__ __launch_bounds__(256) void th_k(const float* __restrict__ feat,
                                            const float* __restrict__ obj,
                                            float* __restrict__ featT,
                                            uint32_t* __restrict__ hist) {
    __shared__ float tile[32][257];          // +1 pad: load-phase bank spread
    __shared__ uint32_t h[HBINS];
    const int tid = threadIdx.x, bid = blockIdx.x;

    if (bid < 118) {                         // hist part (30000 float4s)
        for (int i = tid; i < HBINS; i += 256) h[i] = 0u;
        __syncthreads();
        const int i = bid * 256 + tid;
        if (i < N_ANCH / 4) {
            float4 v = ((const float4*)obj)[i];
            atomicAdd(&h[fkey(v.x) >> 20], 1u);
            atomicAdd(&h[fkey(v.y) >> 20], 1u);
            atomicAdd(&h[fkey(v.z) >> 20], 1u);
            atomicAdd(&h[fkey(v.w) >> 20], 1u);
        }
        __syncthreads();
        for (int i2 = tid; i2 < HBINS; i2 += 256)
            if (h[i2]) atomicAdd(&hist[i2], h[i2]);
    }

    const int P0 = bid * 32;
    const int pl = tid & 31, c0 = tid >> 5;  // 32 pixels x 8 channel-phases
#pragma unroll
    for (int k = 0; k < 32; ++k)
        tile[pl][k * 8 + c0] = feat[(size_t)(k * 8 + c0) * (FH * FW) + P0 + pl];
    __syncthreads();
#pragma unroll
    for (int m = 0; m < 32; ++m)
        featT[(size_t)(P0 + m) * FC + tid] = tile[m][tid];
}

// ---------------------------------------------------------------------------
// Kernel 1b (fallback): round-2 histogram (grid-stride, 256 blocks).
// ---------------------------------------------------------------------------
__global__ __launch_bounds__(256) void hist_k(const float* __restrict__ obj,
                                              uint32_t* __restrict__ hist) {
    __shared__ uint32_t h[HBINS];
    for (int i = threadIdx.x; i < HBINS; i += 256) h[i] = 0u;
    __syncthreads();
    const float4* o4 = (const float4*)obj;
    for (int i = blockIdx.x * 256 + threadIdx.x; i < N_ANCH / 4; i += gridDim.x * 256) {
        float4 v = o4[i];
        atomicAdd(&h[fkey(v.x) >> 20], 1u);
        atomicAdd(&h[fkey(v.y) >> 20], 1u);
        atomicAdd(&h[fkey(v.z) >> 20], 1u);
        atomicAdd(&h[fkey(v.w) >> 20], 1u);
    }
    __syncthreads();
    for (int i = threadIdx.x; i < HBINS; i += 256)
        if (h[i]) atomicAdd(&hist[i], h[i]);
}

// ---------------------------------------------------------------------------
// Kernel 2 (fused resolve+gather) — round-2 version.
// ---------------------------------------------------------------------------
__global__ __launch_bounds__(256) void gather_k(const float* __restrict__ obj,
                                                const uint32_t* __restrict__ hist,
                                                Ws* __restrict__ ws) {
    __shared__ uint32_t wsum[4];
    __shared__ uint32_t sT;
    const int tid = threadIdx.x;
    const int lane = tid & 63, wave = tid >> 6;
    uint32_t c[16]; uint32_t s = 0;
#pragma unroll
    for (int k = 0; k < 16; ++k) { c[k] = hist[HBINS - 1 - (16 * tid + k)]; s += c[k]; }
    uint32_t incl = s;
    for (int off = 1; off < 64; off <<= 1) {
        uint32_t t = __shfl_up(incl, off);
        if (lane >= off) incl += t;
    }
    if (lane == 63) wsum[wave] = incl;
    __syncthreads();
    uint32_t wpre = 0;
    for (int w2 = 0; w2 < wave; ++w2) wpre += wsum[w2];
    uint32_t before = wpre + incl - s;
#pragma unroll
    for (int k = 0; k < 16; ++k) {
        uint32_t after = before + c[k];
        if (before < K_PRE && after >= K_PRE)
            sT = (uint32_t)(HBINS - 1 - (16 * tid + k)) << 20;
        before = after;
    }
    __syncthreads();
    const uint32_t T = sT;
    int i = blockIdx.x * 256 + tid;
    if (i >= N_ANCH / 4) return;
    float4 v = ((const float4*)obj)[i];
    float vals[4] = {v.x, v.y, v.z, v.w};
#pragma unroll
    for (int k = 0; k < 4; ++k) {
        uint32_t u = fkey(vals[k]);
        if (u >= T) {
            uint32_t pos = atomicAdd(&ws->cnt, 1u);
            if (pos < CAP)
                ws->combo[pos] = ((u64)(~u) << 32) | (uint32_t)(4 * i + k);
        }
    }
}

// ---------------------------------------------------------------------------
// Kernel 3: RANK-based ordering + decode — round-2 version.
// ---------------------------------------------------------------------------
__global__ __launch_bounds__(256) void rank_decode_k(const float* __restrict__ deltas,
                                                     const float* __restrict__ anchors,
                                                     Ws* __restrict__ ws) {
    __shared__ u64 sc[CAP];
    const int tid = threadIdx.x;
    int M = (int)ws->cnt;
    if (M > CAP) M = CAP;
    const int ebase = blockIdx.x * (256 / TPE);
    if (ebase >= M) return;
    for (int e = tid; e < M; e += 256) sc[e] = ws->combo[e];
    __syncthreads();
    const int gid = ebase + tid / TPE;
    const int sub = tid & (TPE - 1);
    if (gid >= M) return;
    const u64 mine = sc[gid];
    int cnt = 0;
    int j = sub;
    for (; j + 3 * TPE < M; j += 4 * TPE) {
        u64 a = sc[j], b = sc[j + TPE], c = sc[j + 2 * TPE], d = sc[j + 3 * TPE];
        cnt += (int)(a < mine) + (int)(b < mine) + (int)(c < mine) + (int)(d < mine);
    }
    for (; j < M; j += TPE) cnt += (int)(sc[j] < mine);
    cnt += __shfl_xor(cnt, 1);
    cnt += __shfl_xor(cnt, 2);
    if (sub == 0 && cnt < K_PRE) {
        const uint32_t idx = (uint32_t)(mine & 0xFFFFFFFFull);
        float a0 = anchors[idx * 4 + 0], a1 = anchors[idx * 4 + 1];
        float a2 = anchors[idx * 4 + 2], a3 = anchors[idx * 4 + 3];
        float d0 = deltas[idx * 4 + 0],  d1 = deltas[idx * 4 + 1];
        float d2 = fminf(deltas[idx * 4 + 2], CLIPV);
        float d3 = fminf(deltas[idx * 4 + 3], CLIPV);
        float w = a2 - a0, h = a3 - a1;
        float cx = a0 + 0.5f * w, cy = a1 + 0.5f * h;
        float pcx = d0 * w + cx, pcy = d1 * h + cy;
        float pw = expf(d2) * w, ph = expf(d3) * h;
        float x1 = fminf(fmaxf(pcx - 0.5f * pw, 0.0f), IMGF);
        float y1 = fminf(fmaxf(pcy - 0.5f * ph, 0.0f), IMGF);
        float x2 = fminf(fmaxf(pcx + 0.5f * pw, 0.0f), IMGF);
        float y2 = fminf(fmaxf(pcy + 0.5f * ph, 0.0f), IMGF);
        ws->cand[cnt] = make_float4(x1, y1, x2, y2);
    }
}

// ---------------------------------------------------------------------------
// Kernel 4: pairwise suppression bitmask — round-2 version.
// ---------------------------------------------------------------------------
__global__ __launch_bounds__(256) void nms_mask_k(Ws* __restrict__ ws) {
    const int i = blockIdx.x;
    const int lane = threadIdx.x & 63;
    const int wave = threadIdx.x >> 6;
    const float4 bi = ws->cand[i];
    const float ai = (bi.z - bi.x) * (bi.w - bi.y);
    for (int wd = wave; wd < NWORD; wd += 4) {
        int j = wd * 64 + lane;
        bool bit = false;
        if (j < K_PRE && j > i) {
            float4 bj = ws->cand[j];
            float aj = (bj.z - bj.x) * (bj.w - bj.y);
            float xx1 = fmaxf(bi.x, bj.x);
            float yy1 = fmaxf(bi.y, bj.y);
            float xx2 = fminf(bi.z, bj.z);
            float yy2 = fminf(bi.w, bj.w);
            float ww = fmaxf(xx2 - xx1, 0.0f);
            float hh = fmaxf(yy2 - yy1, 0.0f);
            float inter = ww * hh;
            float iou = inter / (ai + aj - inter + 1e-6f);
            bit = iou > IOU_THR;
        }
        u64 bal = __ballot(bit);
        if (lane == 0) ws->mask[(size_t)i * NWORD + wd] = bal;
    }
}

// ---------------------------------------------------------------------------
// Kernel 5: greedy scan — round-2 version (measured ~25us standalone).
// ---------------------------------------------------------------------------
__global__ __launch_bounds__(512) void nms_scan_k(Ws* __restrict__ ws) {
    __shared__ __align__(16) u64 sbuf[2][TROWS * NWORD];
    __shared__ int s_stop;
    const int tid = threadIdx.x;
    const int lane = tid & 63;
    const int wave = tid >> 6;
    const int lmod = lane & 31;
    const u64* __restrict__ mask = ws->mask;

    {
        const ulonglong2* src = (const ulonglong2*)mask;
        ulonglong2* dst = (ulonglong2*)sbuf[0];
        for (int e = tid; e < TROWS * NWORD / 2; e += 512) dst[e] = src[e];
    }
    if (tid == 0) s_stop = 0;
    __syncthreads();

    u64 supp = 0ull;
    int kcnt = 0;
    int decided = 0;
    for (int t = 0; t < NTILE; ++t) {
        const int base = t * TROWS;
        const int nb = min(TROWS, K_PRE - base);
        if (wave == 0) {
            const u64* sm = sbuf[t & 1];
            u64 A[CH], B[CH];
#pragma unroll
            for (int b = 0; b < CH; ++b) A[b] = sm[b * NWORD + lmod];
            for (int s = 0; s < nb; s += 2 * CH) {
                const bool hasB = (s + CH) < nb;
                if (hasB) {
#pragma unroll
                    for (int b = 0; b < CH; ++b) B[b] = sm[(s + CH + b) * NWORD + lmod];
                }
                {
                    const int w = (base + s) >> 6;
                    const int bofs = (base + s) & 63;
                    u64 keptw = 0ull;
                    if (lane == w) {
                        u64 cur = supp;
#pragma unroll
                        for (int b = 0; b < CH; ++b) {
                            u64 bit = (cur >> (bofs + b)) & 1ull;
                            u64 sel = bit - 1ull;
                            cur |= A[b] & sel;
                            keptw |= sel & (1ull << b);
                        }
                        supp = cur;
                    }
                    u64 kb = __shfl(keptw, w);
                    kcnt += __popcll(kb);
#pragma unroll
                    for (int b = 0; b < CH; ++b) {
                        u64 sel = 0ull - ((kb >> b) & 1ull);
                        supp |= A[b] & sel;
                    }
                }
                if (hasB) {
                    if (s + 2 * CH < nb) {
#pragma unroll
                        for (int b = 0; b < CH; ++b)
                            A[b] = sm[(s + 2 * CH + b) * NWORD + lmod];
                    }
                    const int w = (base + s + CH) >> 6;
                    const int bofs = (base + s + CH) & 63;
                    u64 keptw = 0ull;
                    if (lane == w) {
                        u64 cur = supp;
#pragma unroll
                        for (int b = 0; b < CH; ++b) {
                            u64 bit = (cur >> (bofs + b)) & 1ull;
                            u64 sel = bit - 1ull;
                            cur |= B[b] & sel;
                            keptw |= sel & (1ull << b);
                        }
                        supp = cur;
                    }
                    u64 kb = __shfl(keptw, w);
                    kcnt += __popcll(kb);
#pragma unroll
                    for (int b = 0; b < CH; ++b) {
                        u64 sel = 0ull - ((kb >> b) & 1ull);
                        supp |= B[b] & sel;
                    }
                }
            }
            decided = base + nb;
            if (lane == 0 && kcnt >= K_POST) s_stop = 1;
        } else if (t + 1 < NTILE) {
            const int nbase = (t + 1) * TROWS;
            const int npairs = (min(TROWS, K_PRE - nbase) * NWORD) / 2;
            const ulonglong2* src = (const ulonglong2*)(mask + (size_t)nbase * NWORD);
            ulonglong2* dst = (ulonglong2*)sbuf[(t + 1) & 1];
            for (int e = tid - 64; e < npairs; e += 448) dst[e] = src[e];
        }
        __syncthreads();
        if (s_stop) break;
    }

    if (wave == 0) {
        u64 valid;
        if (lane < NWORD - 1)       valid = ~0ull;
        else if (lane == NWORD - 1) valid = (1ull << (K_PRE - (NWORD - 1) * 64)) - 1ull;
        else                        valid = 0ull;
        const int dw = decided - lane * 64;
        const u64 dmask = (dw <= 0) ? 0ull : ((dw >= 64) ? ~0ull : ((1ull << dw) - 1ull));
        u64 keepw = (~supp) & valid & dmask;
        int cnt = __popcll(keepw);
        int incl = cnt;
        for (int off = 1; off < 64; off <<= 1) {
            int t = __shfl_up(incl, off);
            if (lane >= off) incl += t;
        }
        int pos = incl - cnt;
        u64 kw = keepw;
        while (kw) {
            int b = __ffsll((unsigned long long)kw) - 1;
            kw &= kw - 1ull;
            if (pos < K_POST) ws->rows[pos] = lane * 64 + b;
            ++pos;
        }
        int total = __shfl(incl, 63);
        if (lane == 0) ws->nk = total;
        int start = total < K_POST ? total : K_POST;
        for (int r = start + lane; r < K_POST; r += 64) ws->rows[r] = -1;
    }
}

// ---------------------------------------------------------------------------
// Kernel 6a (HWC path): ROIAlign over featT. Round-9 theory: the CHW roi_k
// was L2-LINE-BANDWIDTH bound: 8B gathers touched ~64 distinct 64B lines per
// wave-load (~900MB line traffic / 44us ~ 20TB/s ~ L2 ceiling, 8x over-read).
// HWC: thread=(bin p, channel-quad cq); 4 lanes read ONE contiguous 64B
// segment per corner -> 16 lines/wave-load (8x less line traffic). Results
// staged via 3KB LDS so output stores stay fully coalesced. Same (r, cg)
// block mapping as round-2 (2.56MB/XCD phased slices).
// ---------------------------------------------------------------------------
__global__ __launch_bounds__(256) void roi2_k(const float* __restrict__ featT,
                                              const Ws* __restrict__ ws,
                                              float* __restrict__ out) {
    __shared__ float sout[CG * 49];
    const int b = blockIdx.x;
    const int xcd = b & 7;
    const int s = b >> 3;
    const int r = s & (K_POST - 1);
    const int cg = xcd + 8 * (s >> 9);
    const int cbase = cg * CG;
    float* oblk = out + (size_t)r * (FC * 49) + (size_t)cbase * 49;
    const int row = ws->rows[r];
    const int tid = threadIdx.x;

    if (row < 0) {
        for (int e = tid; e < CG * 49; e += 256) oblk[e] = 0.0f;
        return;
    }

    if (tid < 196) {                         // 49 bins x 4 channel-quads
        const int p = tid >> 2;              // bin 0..48
        const int cq = tid & 3;              // quad 0..3 (4 ch each)
        const int oy = p / 7, ox = p % 7;

        const float4 bx = ws->cand[row];
        const float x1 = bx.x * SCALE, y1 = bx.y * SCALE;
        const float x2 = bx.z * SCALE, y2 = bx.w * SCALE;
        const float rw = fmaxf(x2 - x1, 1.0f);
        const float rh = fmaxf(y2 - y1, 1.0f);
        const float stepx = rw / 14.0f;
        const float stepy = rh / 14.0f;

        int    o0[4], o1[4];                 // element offsets of (y0,basex),(y1,basex)
        float4 w4[4];
#pragma unroll
        for (int sub = 0; sub < 4; ++sub) {
            const int sy = sub >> 1, sx = sub & 1;
            float yy = y1 + ((float)(2 * oy + sy) + 0.5f) * stepy;
            float y = fminf(fmaxf(yy, 0.0f), (float)(FH - 1));
            float fy0 = floorf(y);
            int iy0 = (int)fy0;
            int iy1 = min(iy0 + 1, FH - 1);
            float ly = y - fy0;
            float xx = x1 + ((float)(2 * ox + sx) + 0.5f) * stepx;
            float x = fminf(fmaxf(xx, 0.0f), (float)(FW - 1));
            float fx0 = floorf(x);
            int ix0 = (int)fx0;
            float lx = x - fx0;
            float wxl, wxr; int basex;
            if (ix0 >= FW - 1) { basex = FW - 2; wxl = 0.0f; wxr = 1.0f; }
            else               { basex = ix0;    wxl = 1.0f - lx; wxr = lx; }
            float wy0 = 1.0f - ly, wy1 = ly;
            o0[sub] = (iy0 * FW + basex) * FC;
            o1[sub] = (iy1 * FW + basex) * FC;
            w4[sub] = make_float4(wy0 * wxl * 0.25f, wy0 * wxr * 0.25f,
                                  wy1 * wxl * 0.25f, wy1 * wxr * 0.25f);
        }

        // ISSUE PHASE: 16 float4 loads back-to-back (4 lanes -> 64B segment).
        const int cofs = cbase + cq * 4;
        float4 v[16];
#pragma unroll
        for (int sub = 0; sub < 4; ++sub) {
            v[4 * sub + 0] = *(const float4*)(featT + (size_t)o0[sub] + cofs);
            v[4 * sub + 1] = *(const float4*)(featT + (size_t)o0[sub] + FC + cofs);
            v[4 * sub + 2] = *(const float4*)(featT + (size_t)o1[sub] + cofs);
            v[4 * sub + 3] = *(const float4*)(featT + (size_t)o1[sub] + FC + cofs);
        }

        // COMPUTE: bilinear over 4 channels at once.
        float ax = 0.0f, ay = 0.0f, az = 0.0f, aw = 0.0f;
#pragma unroll
        for (int sub = 0; sub < 4; ++sub) {
            const float4 w = w4[sub];
            ax += w.x * v[4*sub].x + w.y * v[4*sub+1].x + w.z * v[4*sub+2].x + w.w * v[4*sub+3].x;
            ay += w.x * v[4*sub].y + w.y * v[4*sub+1].y + w.z * v[4*sub+2].y + w.w * v[4*sub+3].y;
            az += w.x * v[4*sub].z + w.y * v[4*sub+1].z + w.z * v[4*sub+2].z + w.w * v[4*sub+3].z;
            aw += w.x * v[4*sub].w + w.y * v[4*sub+1].w + w.z * v[4*sub+2].w + w.w * v[4*sub+3].w;
        }
        sout[(cq * 4 + 0) * 49 + p] = ax;
        sout[(cq * 4 + 1) * 49 + p] = ay;
        sout[(cq * 4 + 2) * 49 + p] = az;
        sout[(cq * 4 + 3) * 49 + p] = aw;
    }
    __syncthreads();
    for (int e = tid; e < CG * 49; e += 256) oblk[e] = sout[e];   // coalesced
}

// ---------------------------------------------------------------------------
// Kernel 6b (fallback): round-2 roi_k over CHW feature (measured 44us).
// ---------------------------------------------------------------------------
__global__ __launch_bounds__(256) void roi_k(const float* __restrict__ feat,
                                             const Ws* __restrict__ ws,
                                             float* __restrict__ out) {
    const int b = blockIdx.x;
    const int xcd = b & 7;
    const int s = b >> 3;
    const int r = s & (K_POST - 1);
    const int cg = xcd + 8 * (s >> 9);
    const int cbase = cg * CG;
    float* oblk = out + (size_t)r * (FC * 49) + (size_t)cbase * 49;
    const int row = ws->rows[r];
    const int tid = threadIdx.x;

    if (row < 0) {
        for (int e = tid; e < CG * 49; e += 256) oblk[e] = 0.0f;
        return;
    }
    if (tid >= 245) return;

    const int p = tid % 49;
    const int cslot = tid / 49;
    const int oy = p / 7, ox = p % 7;

    const float4 bx = ws->cand[row];
    const float x1 = bx.x * SCALE, y1 = bx.y * SCALE;
    const float x2 = bx.z * SCALE, y2 = bx.w * SCALE;
    const float rw = fmaxf(x2 - x1, 1.0f);
    const float rh = fmaxf(y2 - y1, 1.0f);
    const float stepx = rw / 14.0f;
    const float stepy = rh / 14.0f;

    int    off0[4], off1[4];
    float4 w4[4];
#pragma unroll
    for (int sub = 0; sub < 4; ++sub) {
        const int sy = sub >> 1, sx = sub & 1;
        float yy = y1 + ((float)(2 * oy + sy) + 0.5f) * stepy;
        float y = fminf(fmaxf(yy, 0.0f), (float)(FH - 1));
        float fy0 = floorf(y);
        int iy0 = (int)fy0;
        int iy1 = min(iy0 + 1, FH - 1);
        float ly = y - fy0;
        float xx = x1 + ((float)(2 * ox + sx) + 0.5f) * stepx;
        float x = fminf(fmaxf(xx, 0.0f), (float)(FW - 1));
        float fx0 = floorf(x);
        int ix0 = (int)fx0;
        float lx = x - fx0;
        float wxl, wxr; int base;
        if (ix0 >= FW - 1) { base = FW - 2; wxl = 0.0f; wxr = 1.0f; }
        else               { base = ix0;    wxl = 1.0f - lx; wxr = lx; }
        float wy0 = 1.0f - ly, wy1 = ly;
        off0[sub] = iy0 * FW + base;
        off1[sub] = iy1 * FW + base;
        w4[sub] = make_float4(wy0 * wxl * 0.25f, wy0 * wxr * 0.25f,
                              wy1 * wxl * 0.25f, wy1 * wxr * 0.25f);
    }

    const float* fb = feat + (size_t)cbase * (FH * FW);
    const float* f0 = fb + (size_t)cslot * (FH * FW);
    const float* f1 = fb + (size_t)(cslot + 5) * (FH * FW);
    const float* f2 = fb + (size_t)(cslot + 10) * (FH * FW);
    f2u r0[8], r1[8], r2[8], r3[8];
#pragma unroll
    for (int sub = 0; sub < 4; ++sub) {
        r0[2 * sub]     = *(const f2u*)(f0 + off0[sub]);
        r0[2 * sub + 1] = *(const f2u*)(f0 + off1[sub]);
    }
#pragma unroll
    for (int sub = 0; sub < 4; ++sub) {
        r1[2 * sub]     = *(const f2u*)(f1 + off0[sub]);
        r1[2 * sub + 1] = *(const f2u*)(f1 + off1[sub]);
    }
#pragma unroll
    for (int sub = 0; sub < 4; ++sub) {
        r2[2 * sub]     = *(const f2u*)(f2 + off0[sub]);
        r2[2 * sub + 1] = *(const f2u*)(f2 + off1[sub]);
    }
    const bool has4 = (cslot == 0);
    if (has4) {
        const float* f3 = fb + (size_t)15 * (FH * FW);
#pragma unroll
        for (int sub = 0; sub < 4; ++sub) {
            r3[2 * sub]     = *(const f2u*)(f3 + off0[sub]);
            r3[2 * sub + 1] = *(const f2u*)(f3 + off1[sub]);
        }
    }

    float a0 = 0.0f, a1 = 0.0f, a2 = 0.0f;
#pragma unroll
    for (int sub = 0; sub < 4; ++sub) {
        a0 += w4[sub].x * r0[2 * sub].x + w4[sub].y * r0[2 * sub].y
            + w4[sub].z * r0[2 * sub + 1].x + w4[sub].w * r0[2 * sub + 1].y;
    }
#pragma unroll
    for (int sub = 0; sub < 4; ++sub) {
        a1 += w4[sub].x * r1[2 * sub].x + w4[sub].y * r1[2 * sub].y
            + w4[sub].z * r1[2 * sub + 1].x + w4[sub].w * r1[2 * sub + 1].y;
    }
#pragma unroll
    for (int sub = 0; sub < 4; ++sub) {
        a2 += w4[sub].x * r2[2 * sub].x + w4[sub].y * r2[2 * sub].y
            + w4[sub].z * r2[2 * sub + 1].x + w4[sub].w * r2[2 * sub + 1].y;
    }
    oblk[cslot * 49 + p] = a0;
    oblk[(cslot + 5) * 49 + p] = a1;
    oblk[(cslot + 10) * 49 + p] = a2;

    if (has4) {
        float a3 = 0.0f;
#pragma unroll
        for (int sub = 0; sub < 4; ++sub) {
            a3 += w4[sub].x * r3[2 * sub].x + w4[sub].y * r3[2 * sub].y
                + w4[sub].z * r3[2 * sub + 1].x + w4[sub].w * r3[2 * sub + 1].y;
        }
        oblk[15 * 49 + p] = a3;
    }
}

extern "C" void kernel_launch(void* const* d_in, const int* in_sizes, int n_in,
                              void* d_out, int out_size, void* d_ws, size_t ws_size,
                              hipStream_t stream) {
    const float* feature    = (const float*)d_in[0];
    const float* objectness = (const float*)d_in[1];
    const float* deltas     = (const float*)d_in[2];
    const float* anchors    = (const float*)d_in[3];
    Ws* ws = (Ws*)d_ws;
    uint32_t* hist = (uint32_t*)ws->mask;   // alias: hist lives in (pre-)mask space
    float* out = (float*)d_out;

    // featT (41MB HWC transpose) goes after Ws if the workspace is big enough;
    // otherwise fall back to the proven CHW path (round-2 = 195us).
    const size_t ftOff = (sizeof(Ws) + 255) & ~(size_t)255;
    const size_t need  = ftOff + (size_t)(FH * FW) * FC * sizeof(float);
    const bool hwc = (ws_size >= need);
    float* featT = (float*)((char*)d_ws + ftOff);

    hipLaunchKernelGGL(zero_k, dim3(1), dim3(1024), 0, stream, ws);
    if (hwc) {
        hipLaunchKernelGGL(th_k, dim3(FH * FW / 32), dim3(256), 0, stream,
                           feature, objectness, featT, hist);
    } else {
        hipLaunchKernelGGL(hist_k, dim3(256), dim3(256), 0, stream, objectness, hist);
    }
    hipLaunchKernelGGL(gather_k, dim3((N_ANCH / 4 + 255) / 256), dim3(256), 0, stream,
                       objectness, hist, ws);
    hipLaunchKernelGGL(rank_decode_k, dim3(CAP / (256 / TPE)), dim3(256), 0, stream,
                       deltas, anchors, ws);
    hipLaunchKernelGGL(nms_mask_k, dim3(K_PRE), dim3(256), 0, stream, ws);
    hipLaunchKernelGGL(nms_scan_k, dim3(1), dim3(512), 0, stream, ws);
    if (hwc) {
        hipLaunchKernelGGL(roi2_k, dim3(16 * K_POST), dim3(256), 0, stream,
                           featT, ws, out);
    } else {
        hipLaunchKernelGGL(roi_k, dim3(16 * K_POST), dim3(256), 0, stream,
                           feature, ws, out);
    }
}

// Round 10
// 199.319 us; speedup vs baseline: 1.0458x; 1.0435x over previous
//
#include <hip/hip_runtime.h>
#include <cstdint>
#include <cstddef>

#define N_ANCH   120000
#define K_PRE    2000
#define K_POST   512
#define CAP      4096
#define NWORD    32          // ceil(K_PRE/64)
#define HBINS    4096        // top-12-bit histogram
#define IOU_THR  0.7f
#define IMGF     800.0f
#define CLIPV    4.135166556742356f
#define FH       200
#define FW       200
#define FC       256
#define SCALE    0.25f

#define TROWS    96          // scan tile rows (96*256B = 24KB; x2 buffers = 48KB LDS)
#define NTILE    21          // ceil(2000/96); last tile = 80 rows
#define CH       8           // scan chunk rows (register prefetch depth)

#define CG       16          // roi: channels per group
#define TPE      4           // rank: threads per element

// SESSION LESSONS (measured):
//  - Kernel boundary (~8us) is the cheapest grid barrier on gfx950. grid.sync
//    ~80us/barrier; fence+ticket ~80us; LLC RMW polling +25-40us; relaxed
//    atomic loads can read stale lines (hang).
//  - CHW roi_k is L2-line-bandwidth bound (8x over-read); HWC roi2_k fixes it
//    (round-9: roi2 < 42us, correct). But a SERIAL transpose node eats the
//    gain (~40us). Round-10: hide the transpose inside the scan's dead slot
//    (1-block serial scan leaves 255 CUs idle for ~25us).

typedef unsigned long long u64;
typedef float f2u __attribute__((ext_vector_type(2), aligned(4)));

struct Ws {
    uint32_t T;          // (unused)
    uint32_t cnt;        // gather counter
    int32_t  nk;         // number kept after NMS
    uint32_t pad;
    u64      combo[CAP];             // (~key)<<32 | index (unsorted)
    float4   cand[K_PRE];            // decoded candidate boxes, score-desc order
    int      rows[K_POST];           // candidate rank per output row, -1 = invalid
    u64      mask[(size_t)K_PRE * NWORD];  // IoU bitmask
    // NOTE: first 16KB of mask doubles as the uint32 hist[4096] (used before mask)
};
// featT (HWC transpose, 40000*256 f32 = 41MB) lives AFTER Ws in workspace,
// 256B-aligned — host guards on ws_size and falls back to the CHW path.

// Monotonic float -> uint key (larger float => larger uint). No NaNs expected.
__device__ inline uint32_t fkey(float f) {
    uint32_t u = __float_as_uint(f);
    return (u & 0x80000000u) ? ~u : (u | 0x80000000u);
}

// ---------------------------------------------------------------------------
// Kernel 0: zero the histogram (aliased onto mask region) + counters.
// ---------------------------------------------------------------------------
__global__ __launch_bounds__(1024) void zero_k(Ws* __restrict__ ws) {
    uint32_t* h = (uint32_t*)ws->mask;
    for (int i = threadIdx.x; i < HBINS; i += 1024) h[i] = 0u;
    if (threadIdx.x == 0) { ws->cnt = 0u; ws->nk = 0; ws->T = 0u; }
}

// ---------------------------------------------------------------------------
// Kernel 1: grid-wide histogram (round-2 version, ~6us).
// ---------------------------------------------------------------------------
__global__ __launch_bounds__(256) void hist_k(const float* __restrict__ obj,
                                              uint32_t* __restrict__ hist) {
    __shared__ uint32_t h[HBINS];
    for (int i = threadIdx.x; i < HBINS; i += 256) h[i] = 0u;
    __syncthreads();
    const float4* o4 = (const float4*)obj;
    for (int i = blockIdx.x * 256 + threadIdx.x; i < N_ANCH / 4; i += gridDim.x * 256) {
        float4 v = o4[i];
        atomicAdd(&h[fkey(v.x) >> 20], 1u);
        atomicAdd(&h[fkey(v.y) >> 20], 1u);
        atomicAdd(&h[fkey(v.z) >> 20], 1u);
        atomicAdd(&h[fkey(v.w) >> 20], 1u);
    }
    __syncthreads();
    for (int i = threadIdx.x; i < HBINS; i += 256)
        if (h[i]) atomicAdd(&hist[i], h[i]);
}

// ---------------------------------------------------------------------------
// Kernel 2 (fused resolve+gather) — round-2 version.
// ---------------------------------------------------------------------------
__global__ __launch_bounds__(256) void gather_k(const float* __restrict__ obj,
                                                const uint32_t* __restrict__ hist,
                                                Ws* __restrict__ ws) {
    __shared__ uint32_t wsum[4];
    __shared__ uint32_t sT;
    const int tid = threadIdx.x;
    const int lane = tid & 63, wave = tid >> 6;
    uint32_t c[16]; uint32_t s = 0;
#pragma unroll
    for (int k = 0; k < 16; ++k) { c[k] = hist[HBINS - 1 - (16 * tid + k)]; s += c[k]; }
    uint32_t incl = s;
    for (int off = 1; off < 64; off <<= 1) {
        uint32_t t = __shfl_up(incl, off);
        if (lane >= off) incl += t;
    }
    if (lane == 63) wsum[wave] = incl;
    __syncthreads();
    uint32_t wpre = 0;
    for (int w2 = 0; w2 < wave; ++w2) wpre += wsum[w2];
    uint32_t before = wpre + incl - s;
#pragma unroll
    for (int k = 0; k < 16; ++k) {
        uint32_t after = before + c[k];
        if (before < K_PRE && after >= K_PRE)
            sT = (uint32_t)(HBINS - 1 - (16 * tid + k)) << 20;
        before = after;
    }
    __syncthreads();
    const uint32_t T = sT;
    int i = blockIdx.x * 256 + tid;
    if (i >= N_ANCH / 4) return;
    float4 v = ((const float4*)obj)[i];
    float vals[4] = {v.x, v.y, v.z, v.w};
#pragma unroll
    for (int k = 0; k < 4; ++k) {
        uint32_t u = fkey(vals[k]);
        if (u >= T) {
            uint32_t pos = atomicAdd(&ws->cnt, 1u);
            if (pos < CAP)
                ws->combo[pos] = ((u64)(~u) << 32) | (uint32_t)(4 * i + k);
        }
    }
}

// ---------------------------------------------------------------------------
// Kernel 3: RANK-based ordering + decode — round-2 version.
// ---------------------------------------------------------------------------
__global__ __launch_bounds__(256) void rank_decode_k(const float* __restrict__ deltas,
                                                     const float* __restrict__ anchors,
                                                     Ws* __restrict__ ws) {
    __shared__ u64 sc[CAP];
    const int tid = threadIdx.x;
    int M = (int)ws->cnt;
    if (M > CAP) M = CAP;
    const int ebase = blockIdx.x * (256 / TPE);
    if (ebase >= M) return;
    for (int e = tid; e < M; e += 256) sc[e] = ws->combo[e];
    __syncthreads();
    const int gid = ebase + tid / TPE;
    const int sub = tid & (TPE - 1);
    if (gid >= M) return;
    const u64 mine = sc[gid];
    int cnt = 0;
    int j = sub;
    for (; j + 3 * TPE < M; j += 4 * TPE) {
        u64 a = sc[j], b = sc[j + TPE], c = sc[j + 2 * TPE], d = sc[j + 3 * TPE];
        cnt += (int)(a < mine) + (int)(b < mine) + (int)(c < mine) + (int)(d < mine);
    }
    for (; j < M; j += TPE) cnt += (int)(sc[j] < mine);
    cnt += __shfl_xor(cnt, 1);
    cnt += __shfl_xor(cnt, 2);
    if (sub == 0 && cnt < K_PRE) {
        const uint32_t idx = (uint32_t)(mine & 0xFFFFFFFFull);
        float a0 = anchors[idx * 4 + 0], a1 = anchors[idx * 4 + 1];
        float a2 = anchors[idx * 4 + 2], a3 = anchors[idx * 4 + 3];
        float d0 = deltas[idx * 4 + 0],  d1 = deltas[idx * 4 + 1];
        float d2 = fminf(deltas[idx * 4 + 2], CLIPV);
        float d3 = fminf(deltas[idx * 4 + 3], CLIPV);
        float w = a2 - a0, h = a3 - a1;
        float cx = a0 + 0.5f * w, cy = a1 + 0.5f * h;
        float pcx = d0 * w + cx, pcy = d1 * h + cy;
        float pw = expf(d2) * w, ph = expf(d3) * h;
        float x1 = fminf(fmaxf(pcx - 0.5f * pw, 0.0f), IMGF);
        float y1 = fminf(fmaxf(pcy - 0.5f * ph, 0.0f), IMGF);
        float x2 = fminf(fmaxf(pcx + 0.5f * pw, 0.0f), IMGF);
        float y2 = fminf(fmaxf(pcy + 0.5f * ph, 0.0f), IMGF);
        ws->cand[cnt] = make_float4(x1, y1, x2, y2);
    }
}

// ---------------------------------------------------------------------------
// Kernel 4: pairwise suppression bitmask — round-2 version.
// ---------------------------------------------------------------------------
__global__ __launch_bounds__(256) void nms_mask_k(Ws* __restrict__ ws) {
    const int i = blockIdx.x;
    const int lane = threadIdx.x & 63;
    const int wave = threadIdx.x >> 6;
    const float4 bi = ws->cand[i];
    const float ai = (bi.z - bi.x) * (bi.w - bi.y);
    for (int wd = wave; wd < NWORD; wd += 4) {
        int j = wd * 64 + lane;
        bool bit = false;
        if (j < K_PRE && j > i) {
            float4 bj = ws->cand[j];
            float aj = (bj.z - bj.x) * (bj.w - bj.y);
            float xx1 = fmaxf(bi.x, bj.x);
            float yy1 = fmaxf(bi.y, bj.y);
            float xx2 = fminf(bi.z, bj.z);
            float yy2 = fminf(bi.w, bj.w);
            float ww = fmaxf(xx2 - xx1, 0.0f);
            float hh = fmaxf(yy2 - yy1, 0.0f);
            float inter = ww * hh;
            float iou = inter / (ai + aj - inter + 1e-6f);
            bit = iou > IOU_THR;
        }
        u64 bal = __ballot(bit);
        if (lane == 0) ws->mask[(size_t)i * NWORD + wd] = bal;
    }
}

// ---------------------------------------------------------------------------
// Kernel 5 (round-10): SCAN + TRANSPOSE in one node.
//  Block 0: the proven round-2 greedy scan, at s_setprio(2) so the serial
//  scan wave wins CU issue arbitration vs co-resident transpose waves.
//  Blocks 1..1250: CHW->HWC transpose of one 32-pixel x 256-ch tile each
//  (independent work, consumed only by roi2_k in the NEXT node — the kernel
//  boundary is the barrier; no device-side sync needed). This hides the
//  transpose's ~25us under the scan's ~25us serial window where 255 CUs
//  previously idled. LDS: union of scan sbuf (48KB) and tile (33KB).
// ---------------------------------------------------------------------------
__global__ __launch_bounds__(512) void scan_t_k(const float* __restrict__ feat,
                                                float* __restrict__ featT,
                                                Ws* __restrict__ ws) {
    __shared__ union __align__(16) {
        u64   sbuf[2][TROWS * NWORD];        // 48 KB (scan)
        float tile[32][257];                 // 33 KB (transpose; +1 pad)
    } sm;
    __shared__ int s_stop;
    const int tid = threadIdx.x;
    const int lane = tid & 63;
    const int wave = tid >> 6;

    if (blockIdx.x != 0) {
        // ===================== TRANSPOSE (blocks 1..1250) =====================
        const int P0 = ((int)blockIdx.x - 1) * 32;
        const int pl = tid & 31;
        const int c0 = tid >> 5;             // 0..15 channel phases (512 thr)
#pragma unroll
        for (int k = 0; k < 16; ++k) {
            const int ch = k * 16 + c0;
            sm.tile[pl][ch] = feat[(size_t)ch * (FH * FW) + P0 + pl];
        }
        __syncthreads();
        const int half = tid >> 8;           // 0 or 1
        const int col = tid & 255;
#pragma unroll
        for (int mm = 0; mm < 16; ++mm) {
            const int row = 2 * mm + half;
            featT[(size_t)(P0 + row) * FC + col] = sm.tile[row][col];
        }
        return;
    }

    // ===================== SCAN (block 0) =====================
    __builtin_amdgcn_s_setprio(2);
    const int lmod = lane & 31;
    const u64* __restrict__ mask = ws->mask;
    {
        const ulonglong2* src = (const ulonglong2*)mask;
        ulonglong2* dst = (ulonglong2*)sm.sbuf[0];
        for (int e = tid; e < TROWS * NWORD / 2; e += 512) dst[e] = src[e];
    }
    if (tid == 0) s_stop = 0;
    __syncthreads();

    u64 supp = 0ull;
    int kcnt = 0;
    int decided = 0;
    for (int t = 0; t < NTILE; ++t) {
        const int base = t * TROWS;
        const int nb = min(TROWS, K_PRE - base);
        if (wave == 0) {
            const u64* smb = sm.sbuf[t & 1];
            u64 A[CH], B[CH];
#pragma unroll
            for (int b = 0; b < CH; ++b) A[b] = smb[b * NWORD + lmod];
            for (int s = 0; s < nb; s += 2 * CH) {
                const bool hasB = (s + CH) < nb;
                if (hasB) {
#pragma unroll
                    for (int b = 0; b < CH; ++b) B[b] = smb[(s + CH + b) * NWORD + lmod];
                }
                {
                    const int w = (base + s) >> 6;
                    const int bofs = (base + s) & 63;
                    u64 keptw = 0ull;
                    if (lane == w) {
                        u64 cur = supp;
#pragma unroll
                        for (int b = 0; b < CH; ++b) {
                            u64 bit = (cur >> (bofs + b)) & 1ull;
                            u64 sel = bit - 1ull;
                            cur |= A[b] & sel;
                            keptw |= sel & (1ull << b);
                        }
                        supp = cur;
                    }
                    u64 kb = __shfl(keptw, w);
                    kcnt += __popcll(kb);
#pragma unroll
                    for (int b = 0; b < CH; ++b) {
                        u64 sel = 0ull - ((kb >> b) & 1ull);
                        supp |= A[b] & sel;
                    }
                }
                if (hasB) {
                    if (s + 2 * CH < nb) {
#pragma unroll
                        for (int b = 0; b < CH; ++b)
                            A[b] = smb[(s + 2 * CH + b) * NWORD + lmod];
                    }
                    const int w = (base + s + CH) >> 6;
                    const int bofs = (base + s + CH) & 63;
                    u64 keptw = 0ull;
                    if (lane == w) {
                        u64 cur = supp;
#pragma unroll
                        for (int b = 0; b < CH; ++b) {
                            u64 bit = (cur >> (bofs + b)) & 1ull;
                            u64 sel = bit - 1ull;
                            cur |= B[b] & sel;
                            keptw |= sel & (1ull << b);
                        }
                        supp = cur;
                    }
                    u64 kb = __shfl(keptw, w);
                    kcnt += __popcll(kb);
#pragma unroll
                    for (int b = 0; b < CH; ++b) {
                        u64 sel = 0ull - ((kb >> b) & 1ull);
                        supp |= B[b] & sel;
                    }
                }
            }
            decided = base + nb;
            if (lane == 0 && kcnt >= K_POST) s_stop = 1;
        } else if (t + 1 < NTILE) {
            const int nbase = (t + 1) * TROWS;
            const int npairs = (min(TROWS, K_PRE - nbase) * NWORD) / 2;
            const ulonglong2* src = (const ulonglong2*)(mask + (size_t)nbase * NWORD);
            ulonglong2* dst = (ulonglong2*)sm.sbuf[(t + 1) & 1];
            for (int e = tid - 64; e < npairs; e += 448) dst[e] = src[e];
        }
        __syncthreads();
        if (s_stop) break;
    }

    if (wave == 0) {
        u64 valid;
        if (lane < NWORD - 1)       valid = ~0ull;
        else if (lane == NWORD - 1) valid = (1ull << (K_PRE - (NWORD - 1) * 64)) - 1ull;
        else                        valid = 0ull;
        const int dw = decided - lane * 64;
        const u64 dmask = (dw <= 0) ? 0ull : ((dw >= 64) ? ~0ull : ((1ull << dw) - 1ull));
        u64 keepw = (~supp) & valid & dmask;
        int cnt = __popcll(keepw);
        int incl = cnt;
        for (int off = 1; off < 64; off <<= 1) {
            int t = __shfl_up(incl, off);
            if (lane >= off) incl += t;
        }
        int pos = incl - cnt;
        u64 kw = keepw;
        while (kw) {
            int b = __ffsll((unsigned long long)kw) - 1;
            kw &= kw - 1ull;
            if (pos < K_POST) ws->rows[pos] = lane * 64 + b;
            ++pos;
        }
        int total = __shfl(incl, 63);
        if (lane == 0) ws->nk = total;
        int start = total < K_POST ? total : K_POST;
        for (int r = start + lane; r < K_POST; r += 64) ws->rows[r] = -1;
    }
}

// ---------------------------------------------------------------------------
// Kernel 5b (fallback): round-2 scan (no transpose).
// ---------------------------------------------------------------------------
__global__ __launch_bounds__(512) void nms_scan_k(Ws* __restrict__ ws) {
    __shared__ __align__(16) u64 sbuf[2][TROWS * NWORD];
    __shared__ int s_stop;
    const int tid = threadIdx.x;
    const int lane = tid & 63;
    const int wave = tid >> 6;
    const int lmod = lane & 31;
    const u64* __restrict__ mask = ws->mask;

    {
        const ulonglong2* src = (const ulonglong2*)mask;
        ulonglong2* dst = (ulonglong2*)sbuf[0];
        for (int e = tid; e < TROWS * NWORD / 2; e += 512) dst[e] = src[e];
    }
    if (tid == 0) s_stop = 0;
    __syncthreads();

    u64 supp = 0ull;
    int kcnt = 0;
    int decided = 0;
    for (int t = 0; t < NTILE; ++t) {
        const int base = t * TROWS;
        const int nb = min(TROWS, K_PRE - base);
        if (wave == 0) {
            const u64* sm = sbuf[t & 1];
            u64 A[CH], B[CH];
#pragma unroll
            for (int b = 0; b < CH; ++b) A[b] = sm[b * NWORD + lmod];
            for (int s = 0; s < nb; s += 2 * CH) {
                const bool hasB = (s + CH) < nb;
                if (hasB) {
#pragma unroll
                    for (int b = 0; b < CH; ++b) B[b] = sm[(s + CH + b) * NWORD + lmod];
                }
                {
                    const int w = (base + s) >> 6;
                    const int bofs = (base + s) & 63;
                    u64 keptw = 0ull;
                    if (lane == w) {
                        u64 cur = supp;
#pragma unroll
                        for (int b = 0; b < CH; ++b) {
                            u64 bit = (cur >> (bofs + b)) & 1ull;
                            u64 sel = bit - 1ull;
                            cur |= A[b] & sel;
                            keptw |= sel & (1ull << b);
                        }
                        supp = cur;
                    }
                    u64 kb = __shfl(keptw, w);
                    kcnt += __popcll(kb);
#pragma unroll
                    for (int b = 0; b < CH; ++b) {
                        u64 sel = 0ull - ((kb >> b) & 1ull);
                        supp |= A[b] & sel;
                    }
                }
                if (hasB) {
                    if (s + 2 * CH < nb) {
#pragma unroll
                        for (int b = 0; b < CH; ++b)
                            A[b] = sm[(s + 2 * CH + b) * NWORD + lmod];
                    }
                    const int w = (base + s + CH) >> 6;
                    const int bofs = (base + s + CH) & 63;
                    u64 keptw = 0ull;
                    if (lane == w) {
                        u64 cur = supp;
#pragma unroll
                        for (int b = 0; b < CH; ++b) {
                            u64 bit = (cur >> (bofs + b)) & 1ull;
                            u64 sel = bit - 1ull;
                            cur |= B[b] & sel;
                            keptw |= sel & (1ull << b);
                        }
                        supp = cur;
                    }
                    u64 kb = __shfl(keptw, w);
                    kcnt += __popcll(kb);
#pragma unroll
                    for (int b = 0; b < CH; ++b) {
                        u64 sel = 0ull - ((kb >> b) & 1ull);
                        supp |= B[b] & sel;
                    }
                }
            }
            decided = base + nb;
            if (lane == 0 && kcnt >= K_POST) s_stop = 1;
        } else if (t + 1 < NTILE) {
            const int nbase = (t + 1) * TROWS;
            const int npairs = (min(TROWS, K_PRE - nbase) * NWORD) / 2;
            const ulonglong2* src = (const ulonglong2*)(mask + (size_t)nbase * NWORD);
            ulonglong2* dst = (ulonglong2*)sbuf[(t + 1) & 1];
            for (int e = tid - 64; e < npairs; e += 448) dst[e] = src[e];
        }
        __syncthreads();
        if (s_stop) break;
    }

    if (wave == 0) {
        u64 valid;
        if (lane < NWORD - 1)       valid = ~0ull;
        else if (lane == NWORD - 1) valid = (1ull << (K_PRE - (NWORD - 1) * 64)) - 1ull;
        else                        valid = 0ull;
        const int dw = decided - lane * 64;
        const u64 dmask = (dw <= 0) ? 0ull : ((dw >= 64) ? ~0ull : ((1ull << dw) - 1ull));
        u64 keepw = (~supp) & valid & dmask;
        int cnt = __popcll(keepw);
        int incl = cnt;
        for (int off = 1; off < 64; off <<= 1) {
            int t = __shfl_up(incl, off);
            if (lane >= off) incl += t;
        }
        int pos = incl - cnt;
        u64 kw = keepw;
        while (kw) {
            int b = __ffsll((unsigned long long)kw) - 1;
            kw &= kw - 1ull;
            if (pos < K_POST) ws->rows[pos] = lane * 64 + b;
            ++pos;
        }
        int total = __shfl(incl, 63);
        if (lane == 0) ws->nk = total;
        int start = total < K_POST ? total : K_POST;
        for (int r = start + lane; r < K_POST; r += 64) ws->rows[r] = -1;
    }
}

// ---------------------------------------------------------------------------
// Kernel 6a (HWC path): ROIAlign over featT — round-9 version (verified:
// correct, <42us). 4 lanes read one contiguous 64B segment per corner.
// ---------------------------------------------------------------------------
__global__ __launch_bounds__(256) void roi2_k(const float* __restrict__ featT,
                                              const Ws* __restrict__ ws,
                                              float* __restrict__ out) {
    __shared__ float sout[CG * 49];
    const int b = blockIdx.x;
    const int xcd = b & 7;
    const int s = b >> 3;
    const int r = s & (K_POST - 1);
    const int cg = xcd + 8 * (s >> 9);
    const int cbase = cg * CG;
    float* oblk = out + (size_t)r * (FC * 49) + (size_t)cbase * 49;
    const int row = ws->rows[r];
    const int tid = threadIdx.x;

    if (row < 0) {
        for (int e = tid; e < CG * 49; e += 256) oblk[e] = 0.0f;
        return;
    }

    if (tid < 196) {                         // 49 bins x 4 channel-quads
        const int p = tid >> 2;
        const int cq = tid & 3;
        const int oy = p / 7, ox = p % 7;

        const float4 bx = ws->cand[row];
        const float x1 = bx.x * SCALE, y1 = bx.y * SCALE;
        const float x2 = bx.z * SCALE, y2 = bx.w * SCALE;
        const float rw = fmaxf(x2 - x1, 1.0f);
        const float rh = fmaxf(y2 - y1, 1.0f);
        const float stepx = rw / 14.0f;
        const float stepy = rh / 14.0f;

        int    o0[4], o1[4];
        float4 w4[4];
#pragma unroll
        for (int sub = 0; sub < 4; ++sub) {
            const int sy = sub >> 1, sx = sub & 1;
            float yy = y1 + ((float)(2 * oy + sy) + 0.5f) * stepy;
            float y = fminf(fmaxf(yy, 0.0f), (float)(FH - 1));
            float fy0 = floorf(y);
            int iy0 = (int)fy0;
            int iy1 = min(iy0 + 1, FH - 1);
            float ly = y - fy0;
            float xx = x1 + ((float)(2 * ox + sx) + 0.5f) * stepx;
            float x = fminf(fmaxf(xx, 0.0f), (float)(FW - 1));
            float fx0 = floorf(x);
            int ix0 = (int)fx0;
            float lx = x - fx0;
            float wxl, wxr; int basex;
            if (ix0 >= FW - 1) { basex = FW - 2; wxl = 0.0f; wxr = 1.0f; }
            else               { basex = ix0;    wxl = 1.0f - lx; wxr = lx; }
            float wy0 = 1.0f - ly, wy1 = ly;
            o0[sub] = (iy0 * FW + basex) * FC;
            o1[sub] = (iy1 * FW + basex) * FC;
            w4[sub] = make_float4(wy0 * wxl * 0.25f, wy0 * wxr * 0.25f,
                                  wy1 * wxl * 0.25f, wy1 * wxr * 0.25f);
        }

        const int cofs = cbase + cq * 4;
        float4 v[16];
#pragma unroll
        for (int sub = 0; sub < 4; ++sub) {
            v[4 * sub + 0] = *(const float4*)(featT + (size_t)o0[sub] + cofs);
            v[4 * sub + 1] = *(const float4*)(featT + (size_t)o0[sub] + FC + cofs);
            v[4 * sub + 2] = *(const float4*)(featT + (size_t)o1[sub] + cofs);
            v[4 * sub + 3] = *(const float4*)(featT + (size_t)o1[sub] + FC + cofs);
        }

        float ax = 0.0f, ay = 0.0f, az = 0.0f, aw = 0.0f;
#pragma unroll
        for (int sub = 0; sub < 4; ++sub) {
            const float4 w = w4[sub];
            ax += w.x * v[4*sub].x + w.y * v[4*sub+1].x + w.z * v[4*sub+2].x + w.w * v[4*sub+3].x;
            ay += w.x * v[4*sub].y + w.y * v[4*sub+1].y + w.z * v[4*sub+2].y + w.w * v[4*sub+3].y;
            az += w.x * v[4*sub].z + w.y * v[4*sub+1].z + w.z * v[4*sub+2].z + w.w * v[4*sub+3].z;
            aw += w.x * v[4*sub].w + w.y * v[4*sub+1].w + w.z * v[4*sub+2].w + w.w * v[4*sub+3].w;
        }
        sout[(cq * 4 + 0) * 49 + p] = ax;
        sout[(cq * 4 + 1) * 49 + p] = ay;
        sout[(cq * 4 + 2) * 49 + p] = az;
        sout[(cq * 4 + 3) * 49 + p] = aw;
    }
    __syncthreads();
    for (int e = tid; e < CG * 49; e += 256) oblk[e] = sout[e];   // coalesced
}

// ---------------------------------------------------------------------------
// Kernel 6b (fallback): round-2 roi_k over CHW feature (measured 44us).
// ---------------------------------------------------------------------------
__global__ __launch_bounds__(256) void roi_k(const float* __restrict__ feat,
                                             const Ws* __restrict__ ws,
                                             float* __restrict__ out) {
    const int b = blockIdx.x;
    const int xcd = b & 7;
    const int s = b >> 3;
    const int r = s & (K_POST - 1);
    const int cg = xcd + 8 * (s >> 9);
    const int cbase = cg * CG;
    float* oblk = out + (size_t)r * (FC * 49) + (size_t)cbase * 49;
    const int row = ws->rows[r];
    const int tid = threadIdx.x;

    if (row < 0) {
        for (int e = tid; e < CG * 49; e += 256) oblk[e] = 0.0f;
        return;
    }
    if (tid >= 245) return;

    const int p = tid % 49;
    const int cslot = tid / 49;
    const int oy = p / 7, ox = p % 7;

    const float4 bx = ws->cand[row];
    const float x1 = bx.x * SCALE, y1 = bx.y * SCALE;
    const float x2 = bx.z * SCALE, y2 = bx.w * SCALE;
    const float rw = fmaxf(x2 - x1, 1.0f);
    const float rh = fmaxf(y2 - y1, 1.0f);
    const float stepx = rw / 14.0f;
    const float stepy = rh / 14.0f;

    int    off0[4], off1[4];
    float4 w4[4];
#pragma unroll
    for (int sub = 0; sub < 4; ++sub) {
        const int sy = sub >> 1, sx = sub & 1;
        float yy = y1 + ((float)(2 * oy + sy) + 0.5f) * stepy;
        float y = fminf(fmaxf(yy, 0.0f), (float)(FH - 1));
        float fy0 = floorf(y);
        int iy0 = (int)fy0;
        int iy1 = min(iy0 + 1, FH - 1);
        float ly = y - fy0;
        float xx = x1 + ((float)(2 * ox + sx) + 0.5f) * stepx;
        float x = fminf(fmaxf(xx, 0.0f), (float)(FW - 1));
        float fx0 = floorf(x);
        int ix0 = (int)fx0;
        float lx = x - fx0;
        float wxl, wxr; int base;
        if (ix0 >= FW - 1) { base = FW - 2; wxl = 0.0f; wxr = 1.0f; }
        else               { base = ix0;    wxl = 1.0f - lx; wxr = lx; }
        float wy0 = 1.0f - ly, wy1 = ly;
        off0[sub] = iy0 * FW + base;
        off1[sub] = iy1 * FW + base;
        w4[sub] = make_float4(wy0 * wxl * 0.25f, wy0 * wxr * 0.25f,
                              wy1 * wxl * 0.25f, wy1 * wxr * 0.25f);
    }

    const float* fb = feat + (size_t)cbase * (FH * FW);
    const float* f0 = fb + (size_t)cslot * (FH * FW);
    const float* f1 = fb + (size_t)(cslot + 5) * (FH * FW);
    const float* f2 = fb + (size_t)(cslot + 10) * (FH * FW);
    f2u r0[8], r1[8], r2[8], r3[8];
#pragma unroll
    for (int sub = 0; sub < 4; ++sub) {
        r0[2 * sub]     = *(const f2u*)(f0 + off0[sub]);
        r0[2 * sub + 1] = *(const f2u*)(f0 + off1[sub]);
    }
#pragma unroll
    for (int sub = 0; sub < 4; ++sub) {
        r1[2 * sub]     = *(const f2u*)(f1 + off0[sub]);
        r1[2 * sub + 1] = *(const f2u*)(f1 + off1[sub]);
    }
#pragma unroll
    for (int sub = 0; sub < 4; ++sub) {
        r2[2 * sub]     = *(const f2u*)(f2 + off0[sub]);
        r2[2 * sub + 1] = *(const f2u*)(f2 + off1[sub]);
    }
    const bool has4 = (cslot == 0);
    if (has4) {
        const float* f3 = fb + (size_t)15 * (FH * FW);
#pragma unroll
        for (int sub = 0; sub < 4; ++sub) {
            r3[2 * sub]     = *(const f2u*)(f3 + off0[sub]);
            r3[2 * sub + 1] = *(const f2u*)(f3 + off1[sub]);
        }
    }

    float a0 = 0.0f, a1 = 0.0f, a2 = 0.0f;
#pragma unroll
    for (int sub = 0; sub < 4; ++sub) {
        a0 += w4[sub].x * r0[2 * sub].x + w4[sub].y * r0[2 * sub].y
            + w4[sub].z * r0[2 * sub + 1].x + w4[sub].w * r0[2 * sub + 1].y;
    }
#pragma unroll
    for (int sub = 0; sub < 4; ++sub) {
        a1 += w4[sub].x * r1[2 * sub].x + w4[sub].y * r1[2 * sub].y
            + w4[sub].z * r1[2 * sub + 1].x + w4[sub].w * r1[2 * sub + 1].y;
    }
#pragma unroll
    for (int sub = 0; sub < 4; ++sub) {
        a2 += w4[sub].x * r2[2 * sub].x + w4[sub].y * r2[2 * sub].y
            + w4[sub].z * r2[2 * sub + 1].x + w4[sub].w * r2[2 * sub + 1].y;
    }
    oblk[cslot * 49 + p] = a0;
    oblk[(cslot + 5) * 49 + p] = a1;
    oblk[(cslot + 10) * 49 + p] = a2;

    if (has4) {
        float a3 = 0.0f;
#pragma unroll
        for (int sub = 0; sub < 4; ++sub) {
            a3 += w4[sub].x * r3[2 * sub].x + w4[sub].y * r3[2 * sub].y
                + w4[sub].z * r3[2 * sub + 1].x + w4[sub].w * r3[2 * sub + 1].y;
        }
        oblk[15 * 49 + p] = a3;
    }
}

extern "C" void kernel_launch(void* const* d_in, const int* in_sizes, int n_in,
                              void* d_out, int out_size, void* d_ws, size_t ws_size,
                              hipStream_t stream) {
    const float* feature    = (const float*)d_in[0];
    const float* objectness = (const float*)d_in[1];
    const float* deltas     = (const float*)d_in[2];
    const float* anchors    = (const float*)d_in[3];
    Ws* ws = (Ws*)d_ws;
    uint32_t* hist = (uint32_t*)ws->mask;   // alias: hist lives in (pre-)mask space
    float* out = (float*)d_out;

    // featT (41MB HWC transpose) goes after Ws if the workspace is big enough;
    // otherwise fall back to the proven CHW path (round-2 = 195us).
    const size_t ftOff = (sizeof(Ws) + 255) & ~(size_t)255;
    const size_t need  = ftOff + (size_t)(FH * FW) * FC * sizeof(float);
    const bool hwc = (ws_size >= need);
    float* featT = (float*)((char*)d_ws + ftOff);

    hipLaunchKernelGGL(zero_k, dim3(1), dim3(1024), 0, stream, ws);
    hipLaunchKernelGGL(hist_k, dim3(256), dim3(256), 0, stream, objectness, hist);
    hipLaunchKernelGGL(gather_k, dim3((N_ANCH / 4 + 255) / 256), dim3(256), 0, stream,
                       objectness, hist, ws);
    hipLaunchKernelGGL(rank_decode_k, dim3(CAP / (256 / TPE)), dim3(256), 0, stream,
                       deltas, anchors, ws);
    hipLaunchKernelGGL(nms_mask_k, dim3(K_PRE), dim3(256), 0, stream, ws);
    if (hwc) {
        hipLaunchKernelGGL(scan_t_k, dim3(1 + FH * FW / 32), dim3(512), 0, stream,
                           feature, featT, ws);
        hipLaunchKernelGGL(roi2_k, dim3(16 * K_POST), dim3(256), 0, stream,
                           featT, ws, out);
    } else {
        hipLaunchKernelGGL(nms_scan_k, dim3(1), dim3(512), 0, stream, ws);
        hipLaunchKernelGGL(roi_k, dim3(16 * K_POST), dim3(256), 0, stream,
                           feature, ws, out);
    }
}